// Round 1
// baseline (323.833 us; speedup 1.0000x reference)
//
#include <hip/hip_runtime.h>
#include <math.h>

// YOLO loss: S=7 grid, B=2 boxes, NC=20 classes, IMG=448, GRID=64.
// Inputs (setup_inputs order):
//   0: preConfidence  (N,7,7,2)   f32
//   1: preBoxes       (N,7,7,8)   f32
//   2: preCondClasses (N,7,7,20)  f32
//   3: groundTruth    (N,20,4)    f32   (x1,y1,x2,y2)
//   4: groundLabels   (N,20)      i32
// Output: 4 f32 scalars [coordLoss, objLoss, noObjLoss, clsLoss]

#define S7 7
#define NCELL 49
#define NGT 20
#define NCLS 20
#define BPB 4          // batches per block (one wave each)
#define THREADS 256

__device__ __forceinline__ float clip447(float v) {
    return fminf(fmaxf(v, 0.0f), 447.0f);
}

// IoU of one predicted box (raw cell-relative encoding) vs precomputed GT corners.
__device__ __forceinline__ float iou_one(float4 pb, float ltx, float lty,
                                         float g1x, float g1y, float g2x, float g2y,
                                         float ga) {
    float cx = pb.x * 64.0f + ltx, cy = pb.y * 64.0f + lty;
    float w  = pb.z * 448.0f,      h  = pb.w * 448.0f;
    float p1x = clip447(cx - w * 0.5f), p1y = clip447(cy - h * 0.5f);
    float p2x = clip447(cx + w * 0.5f), p2y = clip447(cy + h * 0.5f);
    float lx = fmaxf(p1x, g1x), ly = fmaxf(p1y, g1y);
    float rx = fminf(p2x, g2x), ry = fminf(p2y, g2y);
    float iw = fmaxf(rx - lx, 0.0f), ih = fmaxf(ry - ly, 0.0f);
    float inter = iw * ih;
    float a1 = (p2x - p1x) * (p2y - p1y);
    return inter / (a1 + ga - inter + 0.0001f);
}

__global__ void zero_out_kernel(float* out) {
    if (threadIdx.x < 4) out[threadIdx.x] = 0.0f;
}

__global__ __launch_bounds__(THREADS) void yolo_loss_kernel(
    const float* __restrict__ preConf,   // N*49*2
    const float* __restrict__ preBoxes,  // N*49*8
    const float* __restrict__ preCls,    // N*49*20
    const float* __restrict__ gtBox,     // N*20*4
    const int*   __restrict__ gtLab,     // N*20
    float* __restrict__ out,             // 4
    int N)
{
    __shared__ int      s_last[BPB][NCELL];
    __shared__ unsigned s_bits[BPB][NCELL];
    __shared__ float    s_off[BPB][NGT][4];
    __shared__ float    s_red[BPB][4];

    const int wave = threadIdx.x >> 6;
    const int lane = threadIdx.x & 63;
    const int n = blockIdx.x * BPB + wave;
    const bool active = (n < N);

    // ---- init per-batch LDS ----
    if (lane < NCELL) {
        s_last[wave][lane] = -1;
        s_bits[wave][lane] = 0u;
    }
    __syncthreads();

    // ---- Phase A: encode ground truth (lanes 0..19) ----
    if (active && lane < NGT) {
        float4 g = reinterpret_cast<const float4*>(gtBox)[(size_t)n * NGT + lane];
        int lab = gtLab[(size_t)n * NGT + lane];
        float w = g.z - g.x, h = g.w - g.y;
        float x = g.x + w * 0.5f, y = g.y + h * 0.5f;
        int cx = (int)floorf(x * 0.015625f);   // /64
        int cy = (int)floorf(y * 0.015625f);
        cx = max(0, min(cx, 6));
        cy = max(0, min(cy, 6));
        int flat = cy * S7 + cx;
        s_off[wave][lane][0] = (x - (float)cx * 64.0f) * 0.015625f;
        s_off[wave][lane][1] = (y - (float)cy * 64.0f) * 0.015625f;
        s_off[wave][lane][2] = w * (1.0f / 448.0f);
        s_off[wave][lane][3] = h * (1.0f / 448.0f);
        atomicMax(&s_last[wave][flat], lane);
        atomicOr(&s_bits[wave][flat], 1u << lab);
    }
    __syncthreads();

    float coordL = 0.0f, objL = 0.0f, noobjL = 0.0f, clsL = 0.0f;

    // ---- Phase B: per-cell boxes/conf (lanes 0..48) ----
    if (active && lane < NCELL) {
        const int c = lane;
        const int row = c / S7, col = c - row * S7;
        const float ltx = (float)col * 64.0f, lty = (float)row * 64.0f;

        float2 cf = reinterpret_cast<const float2*>(preConf)[(size_t)n * NCELL + c];
        int last = s_last[wave][c];
        if (last >= 0) {
            // load only obj cells' boxes (saves HBM on ~2/3 of cells)
            const float4* pbp = reinterpret_cast<const float4*>(preBoxes)
                                + (size_t)n * NCELL * 2 + (size_t)c * 2;
            float4 b0 = pbp[0];
            float4 b1 = pbp[1];

            float gx = s_off[wave][last][0], gy = s_off[wave][last][1];
            float gw = s_off[wave][last][2], gh = s_off[wave][last][3];
            float gcx = gx * 64.0f + ltx, gcy = gy * 64.0f + lty;
            float gW = gw * 448.0f, gH = gh * 448.0f;
            float g1x = clip447(gcx - gW * 0.5f), g1y = clip447(gcy - gH * 0.5f);
            float g2x = clip447(gcx + gW * 0.5f), g2y = clip447(gcy + gH * 0.5f);
            float ga = (g2x - g1x) * (g2y - g1y);

            float iou0 = iou_one(b0, ltx, lty, g1x, g1y, g2x, g2y, ga);
            float iou1 = iou_one(b1, ltx, lty, g1x, g1y, g2x, g2y, ga);
            // jnp.argmax: first max wins -> best=1 only on strict >
            int best = (iou1 > iou0) ? 1 : 0;
            float4 pb = best ? b1 : b0;
            float confB = best ? cf.y : cf.x;
            float confO = best ? cf.x : cf.y;

            float dx = pb.x - gx, dy = pb.y - gy;
            float dw = sqrtf(pb.z) - sqrtf(gw);
            float dh = sqrtf(pb.w) - sqrtf(gh);
            coordL += dx * dx + dy * dy + dw * dw + dh * dh;
            float d = confB - 1.0f;
            objL += d * d;
            noobjL += confO * confO;
        } else {
            noobjL += cf.x * cf.x + cf.y * cf.y;
        }
    }

    // ---- Phase C: class loss (all 64 lanes, coalesced, load-predicated) ----
    if (active) {
        const float* base = preCls + (size_t)n * NCELL * NCLS;
        for (int e = lane; e < NCELL * NCLS; e += 64) {
            int c = e / NCLS;
            int k = e - c * NCLS;
            unsigned bits = s_bits[wave][c];
            if (bits) {
                float lbl = ((bits >> k) & 1u) ? 1.0f : 0.0f;
                float d = base[e] - lbl;
                clsL += d * d;
            }
        }
    }

    // ---- wave reduce (64 lanes) ----
    for (int off = 32; off > 0; off >>= 1) {
        coordL += __shfl_down(coordL, off);
        objL   += __shfl_down(objL, off);
        noobjL += __shfl_down(noobjL, off);
        clsL   += __shfl_down(clsL, off);
    }
    if (lane == 0) {
        s_red[wave][0] = coordL;
        s_red[wave][1] = objL;
        s_red[wave][2] = noobjL;
        s_red[wave][3] = clsL;
    }
    __syncthreads();

    // ---- block combine + one atomic per output ----
    if (threadIdx.x == 0) {
        float c0 = 0.f, c1 = 0.f, c2 = 0.f, c3 = 0.f;
        for (int w = 0; w < BPB; ++w) {
            c0 += s_red[w][0];
            c1 += s_red[w][1];
            c2 += s_red[w][2];
            c3 += s_red[w][3];
        }
        atomicAdd(&out[0], c0 * 5.0f);   // COORD_W
        atomicAdd(&out[1], c1);
        atomicAdd(&out[2], c2 * 0.5f);   // NOOBJ_W
        atomicAdd(&out[3], c3);
    }
}

extern "C" void kernel_launch(void* const* d_in, const int* in_sizes, int n_in,
                              void* d_out, int out_size, void* d_ws, size_t ws_size,
                              hipStream_t stream) {
    const float* preConf  = (const float*)d_in[0];
    const float* preBoxes = (const float*)d_in[1];
    const float* preCls   = (const float*)d_in[2];
    const float* gtBox    = (const float*)d_in[3];
    const int*   gtLab    = (const int*)d_in[4];
    float* out = (float*)d_out;

    const int N = in_sizes[0] / (NCELL * 2);   // 16384
    const int grid = (N + BPB - 1) / BPB;

    zero_out_kernel<<<1, 64, 0, stream>>>(out);
    yolo_loss_kernel<<<grid, THREADS, 0, stream>>>(
        preConf, preBoxes, preCls, gtBox, gtLab, out, N);
}

// Round 2
// 149.999 us; speedup vs baseline: 2.1589x; 2.1589x over previous
//
#include <hip/hip_runtime.h>
#include <math.h>

// YOLO loss: S=7 grid, B=2 boxes, NC=20 classes, IMG=448, GRID=64.
// Inputs (setup_inputs order):
//   0: preConfidence  (N,7,7,2)   f32
//   1: preBoxes       (N,7,7,8)   f32
//   2: preCondClasses (N,7,7,20)  f32
//   3: groundTruth    (N,20,4)    f32   (x1,y1,x2,y2)
//   4: groundLabels   (N,20)      i32
// Output: 4 f32 scalars [coordLoss, objLoss, noObjLoss, clsLoss]
//
// R1 lesson: 16384 same-cacheline atomicAdds serialized (~215us). Now each
// block writes 4 partials to d_ws (component-major), second kernel reduces.

#define S7 7
#define NCELL 49
#define NGT 20
#define NCLS 20
#define BPB 4          // batches per block (one wave each)
#define THREADS 256
#define NBLK 4096      // 16384 / BPB

__device__ __forceinline__ float clip447(float v) {
    return fminf(fmaxf(v, 0.0f), 447.0f);
}

__device__ __forceinline__ float iou_one(float4 pb, float ltx, float lty,
                                         float g1x, float g1y, float g2x, float g2y,
                                         float ga) {
    float cx = pb.x * 64.0f + ltx, cy = pb.y * 64.0f + lty;
    float w  = pb.z * 448.0f,      h  = pb.w * 448.0f;
    float p1x = clip447(cx - w * 0.5f), p1y = clip447(cy - h * 0.5f);
    float p2x = clip447(cx + w * 0.5f), p2y = clip447(cy + h * 0.5f);
    float lx = fmaxf(p1x, g1x), ly = fmaxf(p1y, g1y);
    float rx = fminf(p2x, g2x), ry = fminf(p2y, g2y);
    float iw = fmaxf(rx - lx, 0.0f), ih = fmaxf(ry - ly, 0.0f);
    float inter = iw * ih;
    float a1 = (p2x - p1x) * (p2y - p1y);
    return inter / (a1 + ga - inter + 0.0001f);
}

__global__ __launch_bounds__(THREADS) void yolo_loss_kernel(
    const float* __restrict__ preConf,   // N*49*2
    const float* __restrict__ preBoxes,  // N*49*8
    const float* __restrict__ preCls,    // N*49*20
    const float* __restrict__ gtBox,     // N*20*4
    const int*   __restrict__ gtLab,     // N*20
    float* __restrict__ ws,              // 4 * NBLK partials, component-major
    int N)
{
    __shared__ int      s_last[BPB][NCELL];
    __shared__ unsigned s_bits[BPB][NCELL];
    __shared__ float    s_off[BPB][NGT][4];
    __shared__ float    s_red[BPB][4];

    const int wave = threadIdx.x >> 6;
    const int lane = threadIdx.x & 63;
    const int n = blockIdx.x * BPB + wave;
    const bool active = (n < N);

    if (lane < NCELL) {
        s_last[wave][lane] = -1;
        s_bits[wave][lane] = 0u;
    }
    __syncthreads();

    // ---- Phase A: encode ground truth (lanes 0..19) ----
    if (active && lane < NGT) {
        float4 g = reinterpret_cast<const float4*>(gtBox)[(size_t)n * NGT + lane];
        int lab = gtLab[(size_t)n * NGT + lane];
        float w = g.z - g.x, h = g.w - g.y;
        float x = g.x + w * 0.5f, y = g.y + h * 0.5f;
        int cx = (int)floorf(x * 0.015625f);   // /64
        int cy = (int)floorf(y * 0.015625f);
        cx = max(0, min(cx, 6));
        cy = max(0, min(cy, 6));
        int flat = cy * S7 + cx;
        s_off[wave][lane][0] = (x - (float)cx * 64.0f) * 0.015625f;
        s_off[wave][lane][1] = (y - (float)cy * 64.0f) * 0.015625f;
        s_off[wave][lane][2] = w * (1.0f / 448.0f);
        s_off[wave][lane][3] = h * (1.0f / 448.0f);
        atomicMax(&s_last[wave][flat], lane);
        atomicOr(&s_bits[wave][flat], 1u << lab);
    }
    __syncthreads();

    float coordL = 0.0f, objL = 0.0f, noobjL = 0.0f, clsL = 0.0f;

    // ---- Phase B: per-cell boxes/conf (lanes 0..48) ----
    if (active && lane < NCELL) {
        const int c = lane;
        const int row = c / S7, col = c - row * S7;
        const float ltx = (float)col * 64.0f, lty = (float)row * 64.0f;

        float2 cf = reinterpret_cast<const float2*>(preConf)[(size_t)n * NCELL + c];
        int last = s_last[wave][c];
        if (last >= 0) {
            const float4* pbp = reinterpret_cast<const float4*>(preBoxes)
                                + (size_t)n * NCELL * 2 + (size_t)c * 2;
            float4 b0 = pbp[0];
            float4 b1 = pbp[1];

            float gx = s_off[wave][last][0], gy = s_off[wave][last][1];
            float gw = s_off[wave][last][2], gh = s_off[wave][last][3];
            float gcx = gx * 64.0f + ltx, gcy = gy * 64.0f + lty;
            float gW = gw * 448.0f, gH = gh * 448.0f;
            float g1x = clip447(gcx - gW * 0.5f), g1y = clip447(gcy - gH * 0.5f);
            float g2x = clip447(gcx + gW * 0.5f), g2y = clip447(gcy + gH * 0.5f);
            float ga = (g2x - g1x) * (g2y - g1y);

            float iou0 = iou_one(b0, ltx, lty, g1x, g1y, g2x, g2y, ga);
            float iou1 = iou_one(b1, ltx, lty, g1x, g1y, g2x, g2y, ga);
            int best = (iou1 > iou0) ? 1 : 0;            // jnp.argmax: first max wins
            float4 pb = best ? b1 : b0;
            float confB = best ? cf.y : cf.x;
            float confO = best ? cf.x : cf.y;

            float dx = pb.x - gx, dy = pb.y - gy;
            float dw = sqrtf(pb.z) - sqrtf(gw);
            float dh = sqrtf(pb.w) - sqrtf(gh);
            coordL += dx * dx + dy * dy + dw * dw + dh * dh;
            float d = confB - 1.0f;
            objL += d * d;
            noobjL += confO * confO;
        } else {
            noobjL += cf.x * cf.x + cf.y * cf.y;
        }
    }

    // ---- Phase C: class loss (all 64 lanes, coalesced, load-predicated) ----
    if (active) {
        const float* base = preCls + (size_t)n * NCELL * NCLS;
        for (int e = lane; e < NCELL * NCLS; e += 64) {
            int c = e / NCLS;
            int k = e - c * NCLS;
            unsigned bits = s_bits[wave][c];
            if (bits) {
                float lbl = ((bits >> k) & 1u) ? 1.0f : 0.0f;
                float d = base[e] - lbl;
                clsL += d * d;
            }
        }
    }

    // ---- wave reduce (64 lanes) ----
    for (int off = 32; off > 0; off >>= 1) {
        coordL += __shfl_down(coordL, off);
        objL   += __shfl_down(objL, off);
        noobjL += __shfl_down(noobjL, off);
        clsL   += __shfl_down(clsL, off);
    }
    if (lane == 0) {
        s_red[wave][0] = coordL;
        s_red[wave][1] = objL;
        s_red[wave][2] = noobjL;
        s_red[wave][3] = clsL;
    }
    __syncthreads();

    // ---- block combine -> ws partials (NO atomics) ----
    if (threadIdx.x == 0) {
        float c0 = 0.f, c1 = 0.f, c2 = 0.f, c3 = 0.f;
        for (int w = 0; w < BPB; ++w) {
            c0 += s_red[w][0];
            c1 += s_red[w][1];
            c2 += s_red[w][2];
            c3 += s_red[w][3];
        }
        ws[0 * NBLK + blockIdx.x] = c0 * 5.0f;   // COORD_W
        ws[1 * NBLK + blockIdx.x] = c1;
        ws[2 * NBLK + blockIdx.x] = c2 * 0.5f;   // NOOBJ_W
        ws[3 * NBLK + blockIdx.x] = c3;
    }
}

// One wave per loss component; coalesced reads of its NBLK partials.
__global__ __launch_bounds__(256) void reduce_kernel(
    const float* __restrict__ ws, float* __restrict__ out)
{
    const int wave = threadIdx.x >> 6;   // 0..3 = component
    const int lane = threadIdx.x & 63;
    const float* src = ws + wave * NBLK;
    float s = 0.0f;
    for (int i = lane; i < NBLK; i += 64) s += src[i];
    for (int off = 32; off > 0; off >>= 1) s += __shfl_down(s, off);
    if (lane == 0) out[wave] = s;
}

extern "C" void kernel_launch(void* const* d_in, const int* in_sizes, int n_in,
                              void* d_out, int out_size, void* d_ws, size_t ws_size,
                              hipStream_t stream) {
    const float* preConf  = (const float*)d_in[0];
    const float* preBoxes = (const float*)d_in[1];
    const float* preCls   = (const float*)d_in[2];
    const float* gtBox    = (const float*)d_in[3];
    const int*   gtLab    = (const int*)d_in[4];
    float* out = (float*)d_out;
    float* ws  = (float*)d_ws;

    const int N = in_sizes[0] / (NCELL * 2);   // 16384

    yolo_loss_kernel<<<NBLK, THREADS, 0, stream>>>(
        preConf, preBoxes, preCls, gtBox, gtLab, ws, N);
    reduce_kernel<<<1, 256, 0, stream>>>(ws, out);
}

// Round 3
// 134.756 us; speedup vs baseline: 2.4031x; 1.1131x over previous
//
#include <hip/hip_runtime.h>
#include <math.h>

// YOLO loss: S=7 grid, B=2 boxes, NC=20 classes, IMG=448, GRID=64.
// Inputs (setup_inputs order):
//   0: preConfidence  (N,7,7,2)   f32
//   1: preBoxes       (N,7,7,8)   f32
//   2: preCondClasses (N,7,7,20)  f32
//   3: groundTruth    (N,20,4)    f32   (x1,y1,x2,y2)
//   4: groundLabels   (N,20)      i32
// Output: 4 f32 scalars [coordLoss, objLoss, noObjLoss, clsLoss]
//
// R1: same-cacheline atomics serialized (~215us) -> block partials in d_ws.
// R2: kernel <40us but latency/VALU-bound; harness reset overhead ~105us is
//     fixed. This round: float4 Phase C (2.5x fewer instr), 2 batches/wave
//     (2048 blocks = exactly 32 waves/CU), halve partial count.

#define S7 7
#define NCELL 49
#define NGT 20
#define NCLS 20
#define BPB 4          // waves (batches) per block per iteration
#define BPW 2          // batches per wave (outer loop)
#define THREADS 256
#define NBLK 2048      // 16384 / (BPB*BPW)

__device__ __forceinline__ float clip447(float v) {
    return fminf(fmaxf(v, 0.0f), 447.0f);
}

__device__ __forceinline__ float iou_one(float4 pb, float ltx, float lty,
                                         float g1x, float g1y, float g2x, float g2y,
                                         float ga) {
    float cx = pb.x * 64.0f + ltx, cy = pb.y * 64.0f + lty;
    float w  = pb.z * 448.0f,      h  = pb.w * 448.0f;
    float p1x = clip447(cx - w * 0.5f), p1y = clip447(cy - h * 0.5f);
    float p2x = clip447(cx + w * 0.5f), p2y = clip447(cy + h * 0.5f);
    float lx = fmaxf(p1x, g1x), ly = fmaxf(p1y, g1y);
    float rx = fminf(p2x, g2x), ry = fminf(p2y, g2y);
    float iw = fmaxf(rx - lx, 0.0f), ih = fmaxf(ry - ly, 0.0f);
    float inter = iw * ih;
    float a1 = (p2x - p1x) * (p2y - p1y);
    return inter / (a1 + ga - inter + 0.0001f);
}

__global__ __launch_bounds__(THREADS) void yolo_loss_kernel(
    const float* __restrict__ preConf,   // N*49*2
    const float* __restrict__ preBoxes,  // N*49*8
    const float* __restrict__ preCls,    // N*49*20
    const float* __restrict__ gtBox,     // N*20*4
    const int*   __restrict__ gtLab,     // N*20
    float* __restrict__ ws)              // 4 * NBLK partials, component-major
{
    __shared__ int      s_last[BPB][NCELL];
    __shared__ unsigned s_bits[BPB][NCELL];
    __shared__ float    s_off[BPB][NGT][4];
    __shared__ float    s_red[BPB][4];

    const int wave = threadIdx.x >> 6;
    const int lane = threadIdx.x & 63;

    float coordL = 0.0f, objL = 0.0f, noobjL = 0.0f, clsL = 0.0f;

    for (int it = 0; it < BPW; ++it) {
        const int n = it * (NBLK * BPB) + blockIdx.x * BPB + wave;

        if (lane < NCELL) {
            s_last[wave][lane] = -1;
            s_bits[wave][lane] = 0u;
        }
        __syncthreads();

        // ---- Phase A: encode ground truth (lanes 0..19) ----
        if (lane < NGT) {
            float4 g = reinterpret_cast<const float4*>(gtBox)[(size_t)n * NGT + lane];
            int lab = gtLab[(size_t)n * NGT + lane];
            float w = g.z - g.x, h = g.w - g.y;
            float x = g.x + w * 0.5f, y = g.y + h * 0.5f;
            int cx = (int)floorf(x * 0.015625f);   // /64
            int cy = (int)floorf(y * 0.015625f);
            cx = max(0, min(cx, 6));
            cy = max(0, min(cy, 6));
            int flat = cy * S7 + cx;
            s_off[wave][lane][0] = (x - (float)cx * 64.0f) * 0.015625f;
            s_off[wave][lane][1] = (y - (float)cy * 64.0f) * 0.015625f;
            s_off[wave][lane][2] = w * (1.0f / 448.0f);
            s_off[wave][lane][3] = h * (1.0f / 448.0f);
            atomicMax(&s_last[wave][flat], lane);
            atomicOr(&s_bits[wave][flat], 1u << lab);
        }
        __syncthreads();

        // ---- Phase B: per-cell boxes/conf (lanes 0..48) ----
        if (lane < NCELL) {
            const int c = lane;
            const int row = c / S7, col = c - row * S7;
            const float ltx = (float)col * 64.0f, lty = (float)row * 64.0f;

            float2 cf = reinterpret_cast<const float2*>(preConf)[(size_t)n * NCELL + c];
            int last = s_last[wave][c];
            if (last >= 0) {
                const float4* pbp = reinterpret_cast<const float4*>(preBoxes)
                                    + (size_t)n * NCELL * 2 + (size_t)c * 2;
                float4 b0 = pbp[0];
                float4 b1 = pbp[1];

                float gx = s_off[wave][last][0], gy = s_off[wave][last][1];
                float gw = s_off[wave][last][2], gh = s_off[wave][last][3];
                float gcx = gx * 64.0f + ltx, gcy = gy * 64.0f + lty;
                float gW = gw * 448.0f, gH = gh * 448.0f;
                float g1x = clip447(gcx - gW * 0.5f), g1y = clip447(gcy - gH * 0.5f);
                float g2x = clip447(gcx + gW * 0.5f), g2y = clip447(gcy + gH * 0.5f);
                float ga = (g2x - g1x) * (g2y - g1y);

                float iou0 = iou_one(b0, ltx, lty, g1x, g1y, g2x, g2y, ga);
                float iou1 = iou_one(b1, ltx, lty, g1x, g1y, g2x, g2y, ga);
                int best = (iou1 > iou0) ? 1 : 0;        // jnp.argmax: first max wins
                float4 pb = best ? b1 : b0;
                float confB = best ? cf.y : cf.x;
                float confO = best ? cf.x : cf.y;

                float dx = pb.x - gx, dy = pb.y - gy;
                float dw = sqrtf(pb.z) - sqrtf(gw);
                float dh = sqrtf(pb.w) - sqrtf(gh);
                coordL += dx * dx + dy * dy + dw * dw + dh * dh;
                float d = confB - 1.0f;
                objL += d * d;
                noobjL += confO * confO;
            } else {
                noobjL += cf.x * cf.x + cf.y * cf.y;
            }
        }

        // ---- Phase C: class loss, float4-vectorized, load-predicated ----
        {
            const float4* base4 = reinterpret_cast<const float4*>(
                preCls + (size_t)n * (NCELL * NCLS));
            #pragma unroll
            for (int t = 0; t < 4; ++t) {
                const int i = lane + t * 64;             // 245 float4s total
                if (i < 245) {
                    const int e = i * 4;
                    const int c0 = e / NCLS;
                    const int k0 = e - c0 * NCLS;
                    const unsigned b0 = s_bits[wave][c0];
                    const bool cross = (k0 > NCLS - 4);
                    const unsigned b1 = cross ? s_bits[wave][c0 + 1] : b0;
                    if (b0 | b1) {
                        float4 v = base4[i];
                        float vv[4] = {v.x, v.y, v.z, v.w};
                        #pragma unroll
                        for (int j = 0; j < 4; ++j) {
                            int kj = k0 + j;
                            unsigned bb = (kj < NCLS) ? b0 : b1;
                            int kk = (kj < NCLS) ? kj : kj - NCLS;
                            if (bb) {
                                float d = vv[j] - (float)((bb >> kk) & 1u);
                                clsL += d * d;
                            }
                        }
                    }
                }
            }
        }
        __syncthreads();   // before next iteration's LDS re-init
    }

    // ---- wave reduce (64 lanes) ----
    for (int off = 32; off > 0; off >>= 1) {
        coordL += __shfl_down(coordL, off);
        objL   += __shfl_down(objL, off);
        noobjL += __shfl_down(noobjL, off);
        clsL   += __shfl_down(clsL, off);
    }
    if (lane == 0) {
        s_red[wave][0] = coordL;
        s_red[wave][1] = objL;
        s_red[wave][2] = noobjL;
        s_red[wave][3] = clsL;
    }
    __syncthreads();

    if (threadIdx.x == 0) {
        float c0 = 0.f, c1 = 0.f, c2 = 0.f, c3 = 0.f;
        for (int w = 0; w < BPB; ++w) {
            c0 += s_red[w][0];
            c1 += s_red[w][1];
            c2 += s_red[w][2];
            c3 += s_red[w][3];
        }
        ws[0 * NBLK + blockIdx.x] = c0 * 5.0f;   // COORD_W
        ws[1 * NBLK + blockIdx.x] = c1;
        ws[2 * NBLK + blockIdx.x] = c2 * 0.5f;   // NOOBJ_W
        ws[3 * NBLK + blockIdx.x] = c3;
    }
}

// One wave per loss component; coalesced reads of its NBLK partials.
__global__ __launch_bounds__(256) void reduce_kernel(
    const float* __restrict__ ws, float* __restrict__ out)
{
    const int wave = threadIdx.x >> 6;   // 0..3 = component
    const int lane = threadIdx.x & 63;
    const float* src = ws + wave * NBLK;
    float s = 0.0f;
    for (int i = lane; i < NBLK; i += 64) s += src[i];
    for (int off = 32; off > 0; off >>= 1) s += __shfl_down(s, off);
    if (lane == 0) out[wave] = s;
}

extern "C" void kernel_launch(void* const* d_in, const int* in_sizes, int n_in,
                              void* d_out, int out_size, void* d_ws, size_t ws_size,
                              hipStream_t stream) {
    const float* preConf  = (const float*)d_in[0];
    const float* preBoxes = (const float*)d_in[1];
    const float* preCls   = (const float*)d_in[2];
    const float* gtBox    = (const float*)d_in[3];
    const int*   gtLab    = (const int*)d_in[4];
    float* out = (float*)d_out;
    float* ws  = (float*)d_ws;

    yolo_loss_kernel<<<NBLK, THREADS, 0, stream>>>(
        preConf, preBoxes, preCls, gtBox, gtLab, ws);
    reduce_kernel<<<1, 256, 0, stream>>>(ws, out);
}